// Round 10
// baseline (183.383 us; speedup 1.0000x reference)
//
#include <hip/hip_runtime.h>
#include <math.h>

#define BS   8
#define NPTS 2048
#define CCH  12      // channels per flow
#define NF   2       // flow dim
#define DIM  24      // NF*CCH, feats order: d = f*12 + c
#define KTOP 16
#define NWV  16      // waves per fused block (1024 threads)
#define P1C  64      // pass-1 candidates per wave (16*64 = 1024 = half)
#define P2C  128     // pass-2 candidates per wave (16*128 = 2048 = all)
#define CBUF 64      // collected-candidate slots per row (expected ~32)
#define CBS  65      // padded stride

#define NROWS    (BS * NPTS)
#define TGT_BASE (NROWS * KTOP * CCH)   // 3145728

typedef unsigned long long u64;
typedef unsigned int       u32;

// ws layout (bytes): feats [NROWS][DIM] | raw [NROWS][CCH]
#define WS_FEATS 0
#define WS_RAW   (NROWS * DIM * 4)                 // 1572864

// Emulate np.linalg.norm(v) + 1e-8 in float32 exactly (numpy pairwise sum, n=24):
//   r[j] = (s[j] + s[j+8]) + s[j+16];  res = ((r0+r1)+(r2+r3)) + ((r4+r5)+(r6+r7))
__device__ __forceinline__ float np_norm_den(const float* __restrict__ v)
{
#pragma clang fp contract(off)
    float s[DIM];
    #pragma unroll
    for (int d = 0; d < DIM; ++d) s[d] = v[d] * v[d];
    float r[8];
    #pragma unroll
    for (int j = 0; j < 8; ++j) r[j] = (s[j] + s[j + 8]) + s[j + 16];
    float res = ((r[0] + r[1]) + (r[2] + r[3])) + ((r[4] + r[5]) + (r[6] + r[7]));
    return sqrtf(res) + 1e-8f;
}

// Monotone float -> u32 (preserves total order for finite floats)
__device__ __forceinline__ u32 ordf(float f)
{
    u32 u = __float_as_uint(f);
    return ((int)u >= 0) ? (u | 0x80000000u) : ~u;
}

// ---------------------------------------------------------------------------
// Kernel 0: normalize every row (numpy-exact fp32), write contiguous feats,
// raw flow-slice (gather-friendly), and the tgt_out output.  (unchanged)
// ---------------------------------------------------------------------------
__global__ __launch_bounds__(256) void prep_kernel(
    const float* __restrict__ x_c,     // [8][12][2][2048]
    const int*   __restrict__ flow_p,
    float*       __restrict__ feats,   // [NROWS][DIM] normalized
    float*       __restrict__ raw,     // [NROWS][CCH] raw flow slice
    float*       __restrict__ out)
{
    const int t = blockIdx.x * 256 + threadIdx.x;   // global row
    const int b = t >> 11;
    const int n = t & (NPTS - 1);
    const float* xb = x_c + (size_t)b * CCH * NF * NPTS;

    float v[DIM];
    {
#pragma clang fp contract(off)
        #pragma unroll
        for (int c = 0; c < CCH; ++c)
            #pragma unroll
            for (int f = 0; f < NF; ++f)
                v[f * CCH + c] = xb[(c * NF + f) * NPTS + n];

        const float den = np_norm_den(v);
        float* fo = feats + (size_t)t * DIM;
        #pragma unroll
        for (int d = 0; d < DIM; ++d) fo[d] = v[d] / den;
    }

    const int flow = flow_p[0];
    float* ro = raw + (size_t)t * CCH;
    #pragma unroll
    for (int c = 0; c < CCH; ++c) {
        const float xv = flow ? v[CCH + c] : v[c];   // raw value, pre-norm
        ro[c] = xv;
        out[TGT_BASE + ((size_t)b * CCH + c) * NPTS + n] = xv;   // tgt_out
    }
}

// ---------------------------------------------------------------------------
// Fused kernel: block = (b, 64-row chunk), 1024 thr = 16 waves; lane = row.
// Pass 1 (HALF the candidates, values only): wave w scans cands [w*64,+64),
// keeps per-row top-16 VALUES (f32 min/max bitonic). 16-way merge -> lb =
// exact 16th-largest of the first 1024 cands, a LOWER BOUND on the true v16
// (order statistic of a subset). Pass 2: recompute dots over ALL 2048
// (bit-identical FMA chain), collect acc >= lb (~32/row) into LDS. Final:
// exact top-16 of collected u64 keys (value desc, index asc), then gather.
// ---------------------------------------------------------------------------
__global__ __launch_bounds__(1024) void fused_topk_kernel(
    const float* __restrict__ feats,
    const float* __restrict__ raw,
    float*       __restrict__ out)
{
    __shared__ float vkeys[NWV][KTOP][64];   // 64 KiB: per-wave sorted value lists
    __shared__ u64   cbuf[64 * CBS];         // 32.5 KiB: collected (val,idx) keys
    __shared__ float v16s[64];
    __shared__ int   cnt[64];
    __shared__ int   sel[64][KTOP];          // 4 KiB

    const int tid  = threadIdx.x;
    const int lane = tid & 63;
    const int w    = __builtin_amdgcn_readfirstlane(tid >> 6);  // uniform wave id
    const int b     = blockIdx.x >> 5;
    const int chunk = blockIdx.x & 31;
    const int row   = b * NPTS + chunk * 64 + lane;

    if (tid < 64) cnt[tid] = 0;

    // own row's normalized vector (per-lane)
    float rfn[DIM];
    {
        const float* fr = feats + (size_t)row * DIM;
        #pragma unroll
        for (int d = 0; d < DIM; ++d) rfn[d] = fr[d];
    }

    const float* cbb = feats + (size_t)b * NPTS * DIM;   // batch candidate base

    // ---- Pass 1: top-16 VALUES over first half (wave w: [w*64, w*64+64)) ----
    float vlist[KTOP];
    #pragma unroll
    for (int k = 0; k < KTOP; ++k) vlist[k] = -3.0f;   // < any cosine

    const int p1_0 = w * P1C;
    for (int jb = 0; jb < P1C; jb += 16) {
        float bv[16];
        #pragma unroll 4
        for (int jj = 0; jj < 16; ++jj) {
            const float* cp = cbb + (size_t)(p1_0 + jb + jj) * DIM;  // wave-uniform
            float acc = 0.0f;
            #pragma unroll
            for (int d = 0; d < DIM; ++d)
                acc = __builtin_fmaf(cp[d], rfn[d], acc);            // exact chain
            bv[jj] = acc;
        }
        // bitonic sort 16 ASCENDING (min/max CEs)
        #pragma unroll
        for (int k = 2; k <= 16; k <<= 1)
            #pragma unroll
            for (int j = k >> 1; j > 0; j >>= 1)
                #pragma unroll
                for (int i = 0; i < 16; ++i) {
                    const int l = i | j;
                    if (l > i) {
                        const float a = bv[i], c = bv[l];
                        if ((i & k) == 0) { bv[i] = fminf(a, c); bv[l] = fmaxf(a, c); }
                        else              { bv[i] = fmaxf(a, c); bv[l] = fminf(a, c); }
                    }
                }
        // merge (list desc + batch asc -> bitonic), then cleanup desc
        #pragma unroll
        for (int i = 0; i < 16; ++i) vlist[i] = fmaxf(vlist[i], bv[i]);
        #pragma unroll
        for (int j = 8; j > 0; j >>= 1)
            #pragma unroll
            for (int i = 0; i < 16; ++i) {
                const int l = i | j;
                if (l > i) {
                    const float a = vlist[i], c = vlist[l];
                    vlist[i] = fmaxf(a, c);
                    vlist[l] = fminf(a, c);
                }
            }
    }

    #pragma unroll
    for (int k = 0; k < KTOP; ++k) vkeys[w][k][lane] = vlist[k];
    __syncthreads();

    // ---- lb: 16-way merge of sorted value lists, take the 16th ----
    if (tid < 64) {
        int h[NWV];
        #pragma unroll
        for (int j = 0; j < NWV; ++j) h[j] = 0;
        float last = -4.0f;
        for (int k = 0; k < KTOP; ++k) {
            float best = -4.0f; int bj = 0;
            #pragma unroll
            for (int j = 0; j < NWV; ++j) {
                const float v = vkeys[j][h[j]][tid];
                if (v > best) { best = v; bj = j; }
            }
            h[bj]++;
            last = best;
        }
        v16s[tid] = last;   // lower bound on the row's true v16
    }
    __syncthreads();

    const float lb = v16s[lane];

    // ---- Pass 2: all 2048 cands, identical chain, collect acc >= lb ----
    const int p2_0 = w * P2C;
    #pragma unroll 4
    for (int j = 0; j < P2C; ++j) {
        const float* cp = cbb + (size_t)(p2_0 + j) * DIM;   // wave-uniform
        float acc = 0.0f;
        #pragma unroll
        for (int d = 0; d < DIM; ++d)
            acc = __builtin_fmaf(cp[d], rfn[d], acc);       // exact chain
        if (acc >= lb) {
            const int p = atomicAdd(&cnt[lane], 1);
            if (p < CBUF)
                cbuf[lane * CBS + p] =
                    ((u64)ordf(acc) << 32) | (u32)(2047 - (p2_0 + j));
        }
    }
    __syncthreads();

    // ---- final per-row exact top-16 of collected keys ----
    if (tid < 64) {
        const int e = (cnt[tid] < CBUF) ? cnt[tid] : CBUF;
        u64* rowbuf = &cbuf[tid * CBS];
        for (int k = 0; k < KTOP; ++k) {
            u64 best = 0; int bp = 0;
            for (int p = 0; p < e; ++p) {
                const u64 v = rowbuf[p];
                if (v > best) { best = v; bp = p; }
            }
            rowbuf[bp] = 0;
            sel[tid][k] = 2047 - (int)(best & 0xFFFFFFFFull);
        }
    }
    __syncthreads();

    // ---- gather: sx_c[b, n, k, c] = raw[(b*2048 + sel)*12 + c] ----
    const int rb = b * NPTS + chunk * 64;
    for (int e = tid; e < 64 * KTOP * CCH; e += 1024) {
        const int L = e / (KTOP * CCH);
        const int r = e % (KTOP * CCH);
        const int k = r / CCH;
        const int c = r % CCH;
        out[((size_t)(rb + L) * KTOP + k) * CCH + c] =
            raw[((size_t)b * NPTS + sel[L][k]) * CCH + c];
    }
}

// ---------------------------------------------------------------------------
extern "C" void kernel_launch(void* const* d_in, const int* in_sizes, int n_in,
                              void* d_out, int out_size, void* d_ws, size_t ws_size,
                              hipStream_t stream)
{
    const float* x_c    = (const float*)d_in[0];
    const int*   flow_p = (const int*)d_in[1];
    float*       out    = (float*)d_out;

    float* feats = (float*)((char*)d_ws + WS_FEATS);
    float* raw   = (float*)((char*)d_ws + WS_RAW);

    prep_kernel<<<NROWS / 256, 256, 0, stream>>>(x_c, flow_p, feats, raw, out);
    fused_topk_kernel<<<BS * 32, 1024, 0, stream>>>(feats, raw, out);
}

// Round 11
// 122.857 us; speedup vs baseline: 1.4927x; 1.4927x over previous
//
#include <hip/hip_runtime.h>
#include <hip/hip_bf16.h>
#include <math.h>

#define BS   8
#define NPTS 2048
#define CCH  12      // channels per flow
#define NF   2       // flow dim
#define DIM  24      // NF*CCH, feats order: d = f*12 + c
#define KPAD 32      // MFMA K (24 + 8 zero pad)
#define KTOP 16
#define NWV  16      // waves per fused block (1024 threads)
#define CBUF 64      // survivor slots per row
#define CBS  65      // padded stride
#define RS   68      // padded row stride of per-wave C tile (64 rows + pad)

#define NROWS    (BS * NPTS)
#define TGT_BASE (NROWS * KTOP * CCH)   // 3145728

typedef unsigned long long u64;
typedef unsigned int       u32;
typedef unsigned short     u16;
typedef __attribute__((ext_vector_type(8))) short short8;   // bf16x8 MFMA frag
typedef __attribute__((ext_vector_type(4))) float f32x4;

// ws layout (bytes)
#define WS_FEATS 0                                  // fp32 [NROWS][24]
#define WS_RAW   (NROWS * DIM * 4)                  // fp32 [NROWS][12]
#define WS_FHI   (WS_RAW + NROWS * CCH * 4)         // bf16 [NROWS][32]
#define WS_FLO   (WS_FHI + NROWS * KPAD * 2)        // bf16 [NROWS][32]

// Emulate np.linalg.norm(v) + 1e-8 in float32 exactly (numpy pairwise sum, n=24)
__device__ __forceinline__ float np_norm_den(const float* __restrict__ v)
{
#pragma clang fp contract(off)
    float s[DIM];
    #pragma unroll
    for (int d = 0; d < DIM; ++d) s[d] = v[d] * v[d];
    float r[8];
    #pragma unroll
    for (int j = 0; j < 8; ++j) r[j] = (s[j] + s[j + 8]) + s[j + 16];
    float res = ((r[0] + r[1]) + (r[2] + r[3])) + ((r[4] + r[5]) + (r[6] + r[7]));
    return sqrtf(res) + 1e-8f;
}

// Monotone float -> u32 (preserves total order for finite floats)
__device__ __forceinline__ u32 ordf(float f)
{
    u32 u = __float_as_uint(f);
    return ((int)u >= 0) ? (u | 0x80000000u) : ~u;
}

// round-to-nearest-even fp32 -> bf16 bits (finite inputs)
__device__ __forceinline__ u16 bf16_rne(float x)
{
    u32 bits = __float_as_uint(x);
    bits += 0x7fffu + ((bits >> 16) & 1u);
    return (u16)(bits >> 16);
}

// ---------------------------------------------------------------------------
// Kernel 0: normalize rows (numpy-exact fp32); write fp32 feats, bf16 hi/lo
// (K-padded to 32), raw flow slice, and the tgt_out output.
// ---------------------------------------------------------------------------
__global__ __launch_bounds__(256) void prep_kernel(
    const float* __restrict__ x_c,     // [8][12][2][2048]
    const int*   __restrict__ flow_p,
    float*       __restrict__ feats,   // [NROWS][24] normalized fp32
    u16*         __restrict__ fhi,     // [NROWS][32] bf16 hi
    u16*         __restrict__ flo,     // [NROWS][32] bf16 lo
    float*       __restrict__ raw,     // [NROWS][12] raw flow slice
    float*       __restrict__ out)
{
    const int t = blockIdx.x * 256 + threadIdx.x;   // global row
    const int b = t >> 11;
    const int n = t & (NPTS - 1);
    const float* xb = x_c + (size_t)b * CCH * NF * NPTS;

    float v[DIM];
    float fn[DIM];
    {
#pragma clang fp contract(off)
        #pragma unroll
        for (int c = 0; c < CCH; ++c)
            #pragma unroll
            for (int f = 0; f < NF; ++f)
                v[f * CCH + c] = xb[(c * NF + f) * NPTS + n];

        const float den = np_norm_den(v);
        float* fo = feats + (size_t)t * DIM;
        #pragma unroll
        for (int d = 0; d < DIM; ++d) { fn[d] = v[d] / den; fo[d] = fn[d]; }
    }

    u16* ho = fhi + (size_t)t * KPAD;
    u16* lo = flo + (size_t)t * KPAD;
    #pragma unroll
    for (int d = 0; d < DIM; ++d) {
        const u16 hb = bf16_rne(fn[d]);
        const float hf = __uint_as_float((u32)hb << 16);
        ho[d] = hb;
        lo[d] = bf16_rne(fn[d] - hf);
    }
    #pragma unroll
    for (int d = DIM; d < KPAD; ++d) { ho[d] = 0; lo[d] = 0; }

    const int flow = flow_p[0];
    float* ro = raw + (size_t)t * CCH;
    #pragma unroll
    for (int c = 0; c < CCH; ++c) {
        const float xv = flow ? v[CCH + c] : v[c];
        ro[c] = xv;
        out[TGT_BASE + ((size_t)b * CCH + c) * NPTS + n] = xv;
    }
}

// ---------------------------------------------------------------------------
// Fused kernel: block = (b, 64-row chunk), 1024 thr = 16 waves; lane = row.
// MFMA split-bf16 (hihi+hilo+lohi) approx dots; |approx-exact| <~ 1.2e-4.
// Pass 1: per-wave 16-cand tiles -> C to private LDS -> f32 bitonic top-16
// values per row; 16-way merge -> approx v16; thr = v16 - 8e-4 (safe bound).
// Pass 2: recompute approx, collect survivor indices (approx >= thr).
// Exact rescue: bit-exact sequential fp32 FMA chain on survivors only,
// u64-key exact top-16 (value desc, index asc), gather.
// ---------------------------------------------------------------------------
__global__ __launch_bounds__(1024) void fused_topk_kernel(
    const float* __restrict__ feats,
    const u16*   __restrict__ fhi,
    const u16*   __restrict__ flo,
    const float* __restrict__ raw,
    float*       __restrict__ out)
{
    __shared__ float cval[NWV * 16 * RS];   // 69.6 KiB; aliased as vkeys between barriers
    __shared__ u64   ckey[64 * CBS];        // 33.3 KiB
    __shared__ float thr_s[64];
    __shared__ int   cnt[64];
    __shared__ int   sel[64][KTOP];

    const int tid  = threadIdx.x;
    const int lane = tid & 63;
    const int w    = __builtin_amdgcn_readfirstlane(tid >> 6);
    const int b     = blockIdx.x >> 5;
    const int chunk = blockIdx.x & 31;
    const int rb    = chunk * 64;            // row base within batch
    const int p     = lane & 15;             // frag row/col within 16
    const int q     = lane >> 4;             // frag quad

    if (tid < 64) cnt[tid] = 0;

    // A fragments (this block's 64 rows = 4 m-tiles), hi/lo, persistent
    short8 ahi[4], alo[4];
    #pragma unroll
    for (int m = 0; m < 4; ++m) {
        const size_t ae = ((size_t)(b * NPTS + rb + m * 16 + p)) * KPAD + q * 8;
        ahi[m] = *(const short8*)(fhi + ae);
        alo[m] = *(const short8*)(flo + ae);
    }

    float* wval = cval + w * (16 * RS);      // private C tile [16 cand][RS]

    float vlist[KTOP];
    #pragma unroll
    for (int k = 0; k < KTOP; ++k) vlist[k] = -3.0f;

    // ---- Pass 1: approx values + per-row top-16 ----
    for (int t = 0; t < 8; ++t) {
        const int cb0 = w * 128 + t * 16;    // cand base within batch
        const size_t be = ((size_t)(b * NPTS + cb0 + p)) * KPAD + q * 8;
        const short8 bhi = *(const short8*)(fhi + be);
        const short8 blo = *(const short8*)(flo + be);
        #pragma unroll
        for (int m = 0; m < 4; ++m) {
            f32x4 acc = {0.0f, 0.0f, 0.0f, 0.0f};
            acc = __builtin_amdgcn_mfma_f32_16x16x32_bf16(ahi[m], bhi, acc, 0, 0, 0);
            acc = __builtin_amdgcn_mfma_f32_16x16x32_bf16(ahi[m], blo, acc, 0, 0, 0);
            acc = __builtin_amdgcn_mfma_f32_16x16x32_bf16(alo[m], bhi, acc, 0, 0, 0);
            // lane holds cand p, rows m*16 + q*4 .. +3
            *(f32x4*)(wval + p * RS + m * 16 + q * 4) = acc;
        }
        // scan this tile's 16 cands for row = lane
        float bv[16];
        #pragma unroll
        for (int j = 0; j < 16; ++j) bv[j] = wval[j * RS + lane];
        // bitonic sort 16 ASC
        #pragma unroll
        for (int k = 2; k <= 16; k <<= 1)
            #pragma unroll
            for (int j = k >> 1; j > 0; j >>= 1)
                #pragma unroll
                for (int i = 0; i < 16; ++i) {
                    const int l = i | j;
                    if (l > i) {
                        const float a = bv[i], c = bv[l];
                        if ((i & k) == 0) { bv[i] = fminf(a, c); bv[l] = fmaxf(a, c); }
                        else              { bv[i] = fmaxf(a, c); bv[l] = fminf(a, c); }
                    }
                }
        // merge + cleanup desc
        #pragma unroll
        for (int i = 0; i < 16; ++i) vlist[i] = fmaxf(vlist[i], bv[i]);
        #pragma unroll
        for (int j = 8; j > 0; j >>= 1)
            #pragma unroll
            for (int i = 0; i < 16; ++i) {
                const int l = i | j;
                if (l > i) {
                    const float a = vlist[i], c = vlist[l];
                    vlist[i] = fmaxf(a, c);
                    vlist[l] = fminf(a, c);
                }
            }
    }

    __syncthreads();                          // all waves done with private cval
    float* vk = cval;                         // alias: vkeys [NWV][KTOP][64]
    #pragma unroll
    for (int k = 0; k < KTOP; ++k) vk[(w * KTOP + k) * 64 + lane] = vlist[k];
    __syncthreads();

    if (tid < 64) {
        int h[NWV];
        #pragma unroll
        for (int j = 0; j < NWV; ++j) h[j] = 0;
        float last = -4.0f;
        for (int k = 0; k < KTOP; ++k) {
            float best = -4.0f; int bj = 0;
            #pragma unroll
            for (int j = 0; j < NWV; ++j) {
                const float v = vk[(j * KTOP + h[j]) * 64 + tid];
                if (v > best) { best = v; bj = j; }
            }
            h[bj]++;
            last = best;
        }
        thr_s[tid] = last - 8e-4f;            // v16_approx - 2*eps
    }
    __syncthreads();                          // thr ready; vk dead, cval reusable

    const float thr = thr_s[lane];

    // ---- Pass 2: recompute approx, collect survivor indices ----
    for (int t = 0; t < 8; ++t) {
        const int cb0 = w * 128 + t * 16;
        const size_t be = ((size_t)(b * NPTS + cb0 + p)) * KPAD + q * 8;
        const short8 bhi = *(const short8*)(fhi + be);
        const short8 blo = *(const short8*)(flo + be);
        #pragma unroll
        for (int m = 0; m < 4; ++m) {
            f32x4 acc = {0.0f, 0.0f, 0.0f, 0.0f};
            acc = __builtin_amdgcn_mfma_f32_16x16x32_bf16(ahi[m], bhi, acc, 0, 0, 0);
            acc = __builtin_amdgcn_mfma_f32_16x16x32_bf16(ahi[m], blo, acc, 0, 0, 0);
            acc = __builtin_amdgcn_mfma_f32_16x16x32_bf16(alo[m], bhi, acc, 0, 0, 0);
            *(f32x4*)(wval + p * RS + m * 16 + q * 4) = acc;
        }
        #pragma unroll
        for (int j = 0; j < 16; ++j) {
            const float v = wval[j * RS + lane];
            if (v >= thr) {
                const int pos = atomicAdd(&cnt[lane], 1);
                if (pos < CBUF)
                    ckey[lane * CBS + pos] = (u64)(u32)(cb0 + j);
            }
        }
    }
    __syncthreads();

    // ---- exact rescue: bit-exact fp32 chain on survivors only ----
    {
        const float* fr = feats + (size_t)(b * NPTS + rb + lane) * DIM;
        float rfn[DIM];
        #pragma unroll
        for (int d = 0; d < DIM; ++d) rfn[d] = fr[d];
        const int e = (cnt[lane] < CBUF) ? cnt[lane] : CBUF;
        for (int pos = w; pos < e; pos += NWV) {
            const int idx = (int)(u32)ckey[lane * CBS + pos];
            const float* cp = feats + (size_t)(b * NPTS + idx) * DIM;
            float acc = 0.0f;
            #pragma unroll
            for (int d = 0; d < DIM; ++d)
                acc = __builtin_fmaf(cp[d], rfn[d], acc);   // exact chain
            ckey[lane * CBS + pos] = ((u64)ordf(acc) << 32) | (u32)(2047 - idx);
        }
    }
    __syncthreads();

    // ---- final exact top-16 per row ----
    if (tid < 64) {
        const int e = (cnt[tid] < CBUF) ? cnt[tid] : CBUF;
        u64* rowbuf = &ckey[tid * CBS];
        for (int k = 0; k < KTOP; ++k) {
            u64 best = 0; int bp = 0;
            for (int pos = 0; pos < e; ++pos) {
                const u64 v = rowbuf[pos];
                if (v > best) { best = v; bp = pos; }
            }
            rowbuf[bp] = 0;
            sel[tid][k] = 2047 - (int)(best & 0xFFFFFFFFull);
        }
    }
    __syncthreads();

    // ---- gather: sx_c[b, n, k, c] = raw[(b*2048 + sel)*12 + c] ----
    const int rg = b * NPTS + rb;
    for (int e = tid; e < 64 * KTOP * CCH; e += 1024) {
        const int L = e / (KTOP * CCH);
        const int r = e % (KTOP * CCH);
        const int k = r / CCH;
        const int c = r % CCH;
        out[((size_t)(rg + L) * KTOP + k) * CCH + c] =
            raw[((size_t)b * NPTS + sel[L][k]) * CCH + c];
    }
}

// ---------------------------------------------------------------------------
extern "C" void kernel_launch(void* const* d_in, const int* in_sizes, int n_in,
                              void* d_out, int out_size, void* d_ws, size_t ws_size,
                              hipStream_t stream)
{
    const float* x_c    = (const float*)d_in[0];
    const int*   flow_p = (const int*)d_in[1];
    float*       out    = (float*)d_out;

    float* feats = (float*)((char*)d_ws + WS_FEATS);
    float* raw   = (float*)((char*)d_ws + WS_RAW);
    u16*   fhi   = (u16*)  ((char*)d_ws + WS_FHI);
    u16*   flo   = (u16*)  ((char*)d_ws + WS_FLO);

    prep_kernel<<<NROWS / 256, 256, 0, stream>>>(x_c, flow_p, feats, fhi, flo, raw, out);
    fused_topk_kernel<<<BS * 32, 1024, 0, stream>>>(feats, fhi, flo, raw, out);
}

// Round 12
// 106.928 us; speedup vs baseline: 1.7150x; 1.1490x over previous
//
#include <hip/hip_runtime.h>
#include <hip/hip_bf16.h>
#include <math.h>

#define BS   8
#define NPTS 2048
#define CCH  12      // channels per flow
#define NF   2       // flow dim
#define DIM  24      // NF*CCH, feats order: d = f*12 + c
#define KPAD 32      // MFMA K (24 + 8 zero pad)
#define KTOP 16
#define NWV  16      // waves per fused block (1024 threads)
#define CBUF 64      // survivor slots per row
#define CBS  65      // padded stride
#define RS   72      // padded row stride of per-wave C tile (16B-aligned, 4-way banks)

#define NROWS    (BS * NPTS)
#define TGT_BASE (NROWS * KTOP * CCH)   // 3145728

typedef unsigned long long u64;
typedef unsigned int       u32;
typedef unsigned short     u16;
typedef __attribute__((ext_vector_type(8))) short short8;   // bf16x8 MFMA frag
typedef __attribute__((ext_vector_type(4))) float f32x4;

// ws layout (bytes)
#define WS_FEATS 0                                  // fp32 [NROWS][24]
#define WS_RAW   (NROWS * DIM * 4)                  // fp32 [NROWS][12]
#define WS_FHI   (WS_RAW + NROWS * CCH * 4)         // bf16 [NROWS][32]
#define WS_FLO   (WS_FHI + NROWS * KPAD * 2)        // bf16 [NROWS][32]

// Emulate np.linalg.norm(v) + 1e-8 in float32 exactly (numpy pairwise sum, n=24)
__device__ __forceinline__ float np_norm_den(const float* __restrict__ v)
{
#pragma clang fp contract(off)
    float s[DIM];
    #pragma unroll
    for (int d = 0; d < DIM; ++d) s[d] = v[d] * v[d];
    float r[8];
    #pragma unroll
    for (int j = 0; j < 8; ++j) r[j] = (s[j] + s[j + 8]) + s[j + 16];
    float res = ((r[0] + r[1]) + (r[2] + r[3])) + ((r[4] + r[5]) + (r[6] + r[7]));
    return sqrtf(res) + 1e-8f;
}

// Monotone float -> u32 (preserves total order for finite floats)
__device__ __forceinline__ u32 ordf(float f)
{
    u32 u = __float_as_uint(f);
    return ((int)u >= 0) ? (u | 0x80000000u) : ~u;
}

// round-to-nearest-even fp32 -> bf16 bits (finite inputs)
__device__ __forceinline__ u16 bf16_rne(float x)
{
    u32 bits = __float_as_uint(x);
    bits += 0x7fffu + ((bits >> 16) & 1u);
    return (u16)(bits >> 16);
}

// ---------------------------------------------------------------------------
// Kernel 0: normalize rows (numpy-exact fp32); write fp32 feats, bf16 hi/lo
// (K-padded to 32), raw flow slice, and the tgt_out output.  (unchanged)
// ---------------------------------------------------------------------------
__global__ __launch_bounds__(256) void prep_kernel(
    const float* __restrict__ x_c,     // [8][12][2][2048]
    const int*   __restrict__ flow_p,
    float*       __restrict__ feats,   // [NROWS][24] normalized fp32
    u16*         __restrict__ fhi,     // [NROWS][32] bf16 hi
    u16*         __restrict__ flo,     // [NROWS][32] bf16 lo
    float*       __restrict__ raw,     // [NROWS][12] raw flow slice
    float*       __restrict__ out)
{
    const int t = blockIdx.x * 256 + threadIdx.x;   // global row
    const int b = t >> 11;
    const int n = t & (NPTS - 1);
    const float* xb = x_c + (size_t)b * CCH * NF * NPTS;

    float v[DIM];
    float fn[DIM];
    {
#pragma clang fp contract(off)
        #pragma unroll
        for (int c = 0; c < CCH; ++c)
            #pragma unroll
            for (int f = 0; f < NF; ++f)
                v[f * CCH + c] = xb[(c * NF + f) * NPTS + n];

        const float den = np_norm_den(v);
        float* fo = feats + (size_t)t * DIM;
        #pragma unroll
        for (int d = 0; d < DIM; ++d) { fn[d] = v[d] / den; fo[d] = fn[d]; }
    }

    u16* ho = fhi + (size_t)t * KPAD;
    u16* lo = flo + (size_t)t * KPAD;
    #pragma unroll
    for (int d = 0; d < DIM; ++d) {
        const u16 hb = bf16_rne(fn[d]);
        const float hf = __uint_as_float((u32)hb << 16);
        ho[d] = hb;
        lo[d] = bf16_rne(fn[d] - hf);
    }
    #pragma unroll
    for (int d = DIM; d < KPAD; ++d) { ho[d] = 0; lo[d] = 0; }

    const int flow = flow_p[0];
    float* ro = raw + (size_t)t * CCH;
    #pragma unroll
    for (int c = 0; c < CCH; ++c) {
        const float xv = flow ? v[CCH + c] : v[c];
        ro[c] = xv;
        out[TGT_BASE + ((size_t)b * CCH + c) * NPTS + n] = xv;
    }
}

// ---------------------------------------------------------------------------
// Fused kernel: block = (b, 64-row chunk), 1024 thr = 16 waves; lane = row.
// MFMA split-bf16 (hihi+hilo+lohi) approx dots; |approx-exact| <~ 1.2e-4.
// Pass 1: per-wave 16-cand tiles -> C to private LDS -> f32 bitonic top-16
// values per row. TOURNAMENT (4 rounds, register bitonic merges) -> exact
// approx-v16 per row; thr = v16 - 8e-4 (safe bound).
// Pass 2: recompute approx, compare IN C-FRAGMENT REGISTERS vs per-position
// thresholds, sparse-append survivor indices via LDS atomics.
// Exact rescue: bit-exact sequential fp32 FMA chain on survivors only.
// Parallel rank-select (16 thr/row): distinct u64 keys -> unique ranks ->
// conflict-free scatter of the exact top-16 (value desc, index asc). Gather.
// ---------------------------------------------------------------------------
__global__ __launch_bounds__(1024) void fused_topk_kernel(
    const float* __restrict__ feats,
    const u16*   __restrict__ fhi,
    const u16*   __restrict__ flo,
    const float* __restrict__ raw,
    float*       __restrict__ out)
{
    __shared__ union {
        float cval[NWV * 16 * RS];   // 72 KiB: pass-1 C tiles, then vkeys[NWV][KTOP][64]
        u64   ckey[64 * CBS];        // 33 KiB: pass-2 survivors (alias, disjoint in time)
    } sh;
    __shared__ float thr_s[64];
    __shared__ int   cnt[64];
    __shared__ int   sel[64][KTOP];

    const int tid  = threadIdx.x;
    const int lane = tid & 63;
    const int w    = __builtin_amdgcn_readfirstlane(tid >> 6);
    const int b     = blockIdx.x >> 5;
    const int chunk = blockIdx.x & 31;
    const int rb    = chunk * 64;            // row base within batch
    const int p     = lane & 15;             // frag row/col within 16
    const int q     = lane >> 4;             // frag quad

    if (tid < 64) cnt[tid] = 0;

    // A fragments (this block's 64 rows = 4 m-tiles), hi/lo, persistent
    short8 ahi[4], alo[4];
    #pragma unroll
    for (int m = 0; m < 4; ++m) {
        const size_t ae = ((size_t)(b * NPTS + rb + m * 16 + p)) * KPAD + q * 8;
        ahi[m] = *(const short8*)(fhi + ae);
        alo[m] = *(const short8*)(flo + ae);
    }

    float* wval = sh.cval + w * (16 * RS);   // private C tile [16 cand][RS]

    float vlist[KTOP];
    #pragma unroll
    for (int k = 0; k < KTOP; ++k) vlist[k] = -3.0f;

    // ---- Pass 1: approx values + per-row top-16 (per wave: 128 cands) ----
    for (int t = 0; t < 8; ++t) {
        const int cb0 = w * 128 + t * 16;    // cand base within batch
        const size_t be = ((size_t)(b * NPTS + cb0 + p)) * KPAD + q * 8;
        const short8 bhi = *(const short8*)(fhi + be);
        const short8 blo = *(const short8*)(flo + be);
        #pragma unroll
        for (int m = 0; m < 4; ++m) {
            f32x4 acc = {0.0f, 0.0f, 0.0f, 0.0f};
            acc = __builtin_amdgcn_mfma_f32_16x16x32_bf16(ahi[m], bhi, acc, 0, 0, 0);
            acc = __builtin_amdgcn_mfma_f32_16x16x32_bf16(ahi[m], blo, acc, 0, 0, 0);
            acc = __builtin_amdgcn_mfma_f32_16x16x32_bf16(alo[m], bhi, acc, 0, 0, 0);
            *(f32x4*)(wval + p * RS + m * 16 + q * 4) = acc;
        }
        float bv[16];
        #pragma unroll
        for (int j = 0; j < 16; ++j) bv[j] = wval[j * RS + lane];
        // bitonic sort 16 ASC
        #pragma unroll
        for (int k = 2; k <= 16; k <<= 1)
            #pragma unroll
            for (int j = k >> 1; j > 0; j >>= 1)
                #pragma unroll
                for (int i = 0; i < 16; ++i) {
                    const int l = i | j;
                    if (l > i) {
                        const float a = bv[i], c = bv[l];
                        if ((i & k) == 0) { bv[i] = fminf(a, c); bv[l] = fmaxf(a, c); }
                        else              { bv[i] = fmaxf(a, c); bv[l] = fminf(a, c); }
                    }
                }
        // merge (list desc + batch asc -> bitonic), cleanup desc
        #pragma unroll
        for (int i = 0; i < 16; ++i) vlist[i] = fmaxf(vlist[i], bv[i]);
        #pragma unroll
        for (int j = 8; j > 0; j >>= 1)
            #pragma unroll
            for (int i = 0; i < 16; ++i) {
                const int l = i | j;
                if (l > i) {
                    const float a = vlist[i], c = vlist[l];
                    vlist[i] = fmaxf(a, c);
                    vlist[l] = fminf(a, c);
                }
            }
    }

    __syncthreads();   // pass-1 tiles dead; cval reusable as vkeys

    // ---- tournament: 4 rounds of pairwise sorted-merge -> exact approx-v16 ----
    float* vk = sh.cval;                     // vkeys[NWV][KTOP][64]
    for (int half = NWV / 2; half >= 1; half >>= 1) {
        if (w >= half && w < 2 * half) {
            #pragma unroll
            for (int k = 0; k < KTOP; ++k)
                vk[(w * KTOP + k) * 64 + lane] = vlist[k];
        }
        __syncthreads();
        if (w < half) {
            float other[KTOP];
            #pragma unroll
            for (int k = 0; k < KTOP; ++k)
                other[k] = vk[((w + half) * KTOP + k) * 64 + lane];
            // mine desc + other reversed (asc) -> elementwise max is bitonic
            #pragma unroll
            for (int i = 0; i < KTOP; ++i)
                vlist[i] = fmaxf(vlist[i], other[KTOP - 1 - i]);
            #pragma unroll
            for (int j = 8; j > 0; j >>= 1)
                #pragma unroll
                for (int i = 0; i < KTOP; ++i) {
                    const int l = i | j;
                    if (l > i) {
                        const float a = vlist[i], c = vlist[l];
                        vlist[i] = fmaxf(a, c);
                        vlist[l] = fminf(a, c);
                    }
                }
        }
        __syncthreads();
    }
    if (w == 0) thr_s[lane] = vlist[KTOP - 1] - 8e-4f;   // v16_approx - 2*eps
    __syncthreads();                          // thr ready; vk dead -> ckey usable

    // per-position thresholds for this lane's C-fragment rows
    float thrv[4][4];
    #pragma unroll
    for (int m = 0; m < 4; ++m)
        #pragma unroll
        for (int i = 0; i < 4; ++i)
            thrv[m][i] = thr_s[m * 16 + q * 4 + i];

    // ---- Pass 2: recompute approx, register compare, sparse append ----
    for (int t = 0; t < 8; ++t) {
        const int cb0 = w * 128 + t * 16;
        const size_t be = ((size_t)(b * NPTS + cb0 + p)) * KPAD + q * 8;
        const short8 bhi = *(const short8*)(fhi + be);
        const short8 blo = *(const short8*)(flo + be);
        #pragma unroll
        for (int m = 0; m < 4; ++m) {
            f32x4 acc = {0.0f, 0.0f, 0.0f, 0.0f};
            acc = __builtin_amdgcn_mfma_f32_16x16x32_bf16(ahi[m], bhi, acc, 0, 0, 0);
            acc = __builtin_amdgcn_mfma_f32_16x16x32_bf16(ahi[m], blo, acc, 0, 0, 0);
            acc = __builtin_amdgcn_mfma_f32_16x16x32_bf16(alo[m], bhi, acc, 0, 0, 0);
            #pragma unroll
            for (int i = 0; i < 4; ++i) {
                if (acc[i] >= thrv[m][i]) {
                    const int r = m * 16 + q * 4 + i;       // row within chunk
                    const int pos = atomicAdd(&cnt[r], 1);
                    if (pos < CBUF)
                        sh.ckey[r * CBS + pos] = (u64)(u32)(cb0 + p);
                }
            }
        }
    }
    __syncthreads();

    // ---- exact rescue: bit-exact fp32 chain on survivors only ----
    {
        const float* fr = feats + (size_t)(b * NPTS + rb + lane) * DIM;
        float rfn[DIM];
        #pragma unroll
        for (int d = 0; d < DIM; ++d) rfn[d] = fr[d];
        const int e = (cnt[lane] < CBUF) ? cnt[lane] : CBUF;
        for (int pos = w; pos < e; pos += NWV) {
            const int idx = (int)(u32)sh.ckey[lane * CBS + pos];
            const float* cp = feats + (size_t)(b * NPTS + idx) * DIM;
            float acc = 0.0f;
            #pragma unroll
            for (int d = 0; d < DIM; ++d)
                acc = __builtin_fmaf(cp[d], rfn[d], acc);   // exact chain
            sh.ckey[lane * CBS + pos] = ((u64)ordf(acc) << 32) | (u32)(2047 - idx);
        }
    }
    __syncthreads();

    // ---- parallel rank-select: 16 threads per row ----
    {
        const int L = tid >> 4;
        const int g = tid & 15;
        const int e = (cnt[L] < CBUF) ? cnt[L] : CBUF;
        const u64* rowbuf = &sh.ckey[L * CBS];
        for (int pos = g; pos < e; pos += 16) {
            const u64 key = rowbuf[pos];
            int rank = 0;
            for (int p2 = 0; p2 < e; ++p2) rank += (rowbuf[p2] > key);
            if (rank < KTOP) sel[L][rank] = 2047 - (int)(key & 0xFFFFFFFFull);
        }
    }
    __syncthreads();

    // ---- gather: sx_c[b, n, k, c] = raw[(b*2048 + sel)*12 + c] ----
    const int rg = b * NPTS + rb;
    for (int e = tid; e < 64 * KTOP * CCH; e += 1024) {
        const int L = e / (KTOP * CCH);
        const int r = e % (KTOP * CCH);
        const int k = r / CCH;
        const int c = r % CCH;
        out[((size_t)(rg + L) * KTOP + k) * CCH + c] =
            raw[((size_t)b * NPTS + sel[L][k]) * CCH + c];
    }
}

// ---------------------------------------------------------------------------
extern "C" void kernel_launch(void* const* d_in, const int* in_sizes, int n_in,
                              void* d_out, int out_size, void* d_ws, size_t ws_size,
                              hipStream_t stream)
{
    const float* x_c    = (const float*)d_in[0];
    const int*   flow_p = (const int*)d_in[1];
    float*       out    = (float*)d_out;

    float* feats = (float*)((char*)d_ws + WS_FEATS);
    float* raw   = (float*)((char*)d_ws + WS_RAW);
    u16*   fhi   = (u16*)  ((char*)d_ws + WS_FHI);
    u16*   flo   = (u16*)  ((char*)d_ws + WS_FLO);

    prep_kernel<<<NROWS / 256, 256, 0, stream>>>(x_c, flow_p, feats, fhi, flo, raw, out);
    fused_topk_kernel<<<BS * 32, 1024, 0, stream>>>(feats, fhi, flo, raw, out);
}

// Round 13
// 105.397 us; speedup vs baseline: 1.7399x; 1.0145x over previous
//
#include <hip/hip_runtime.h>
#include <hip/hip_bf16.h>
#include <math.h>

#define BS   8
#define NPTS 2048
#define CCH  12      // channels per flow
#define NF   2       // flow dim
#define DIM  24      // NF*CCH, feats order: d = f*12 + c
#define KPAD 32      // MFMA K (24 + 8 zero pad)
#define KTOP 16
#define NWV  16      // waves per fused block (1024 threads)
#define CBUF 112     // survivor slots per row (~32 expected, +9.5 sigma)
#define CBS  113     // padded stride
#define RS   72      // padded row stride of per-wave C tile

#define NROWS    (BS * NPTS)
#define TGT_BASE (NROWS * KTOP * CCH)   // 3145728

typedef unsigned long long u64;
typedef unsigned int       u32;
typedef unsigned short     u16;
typedef __attribute__((ext_vector_type(8))) short short8;   // bf16x8 MFMA frag
typedef __attribute__((ext_vector_type(4))) float f32x4;

// ws layout (bytes)
#define WS_FEATS 0                                  // fp32 [NROWS][24]
#define WS_RAW   (NROWS * DIM * 4)                  // fp32 [NROWS][12]
#define WS_FHI   (WS_RAW + NROWS * CCH * 4)         // bf16 [NROWS][32]
#define WS_FLO   (WS_FHI + NROWS * KPAD * 2)        // bf16 [NROWS][32]

// Emulate np.linalg.norm(v) + 1e-8 in float32 exactly (numpy pairwise sum, n=24)
__device__ __forceinline__ float np_norm_den(const float* __restrict__ v)
{
#pragma clang fp contract(off)
    float s[DIM];
    #pragma unroll
    for (int d = 0; d < DIM; ++d) s[d] = v[d] * v[d];
    float r[8];
    #pragma unroll
    for (int j = 0; j < 8; ++j) r[j] = (s[j] + s[j + 8]) + s[j + 16];
    float res = ((r[0] + r[1]) + (r[2] + r[3])) + ((r[4] + r[5]) + (r[6] + r[7]));
    return sqrtf(res) + 1e-8f;
}

// Monotone float -> u32 (preserves total order for finite floats)
__device__ __forceinline__ u32 ordf(float f)
{
    u32 u = __float_as_uint(f);
    return ((int)u >= 0) ? (u | 0x80000000u) : ~u;
}

// round-to-nearest-even fp32 -> bf16 bits (finite inputs)
__device__ __forceinline__ u16 bf16_rne(float x)
{
    u32 bits = __float_as_uint(x);
    bits += 0x7fffu + ((bits >> 16) & 1u);
    return (u16)(bits >> 16);
}

// ---------------------------------------------------------------------------
// Kernel 0: normalize rows (numpy-exact fp32); write fp32 feats, bf16 hi/lo
// (K-padded to 32), raw flow slice, and the tgt_out output.  (unchanged)
// ---------------------------------------------------------------------------
__global__ __launch_bounds__(256) void prep_kernel(
    const float* __restrict__ x_c,     // [8][12][2][2048]
    const int*   __restrict__ flow_p,
    float*       __restrict__ feats,   // [NROWS][24] normalized fp32
    u16*         __restrict__ fhi,     // [NROWS][32] bf16 hi
    u16*         __restrict__ flo,     // [NROWS][32] bf16 lo
    float*       __restrict__ raw,     // [NROWS][12] raw flow slice
    float*       __restrict__ out)
{
    const int t = blockIdx.x * 256 + threadIdx.x;   // global row
    const int b = t >> 11;
    const int n = t & (NPTS - 1);
    const float* xb = x_c + (size_t)b * CCH * NF * NPTS;

    float v[DIM];
    float fn[DIM];
    {
#pragma clang fp contract(off)
        #pragma unroll
        for (int c = 0; c < CCH; ++c)
            #pragma unroll
            for (int f = 0; f < NF; ++f)
                v[f * CCH + c] = xb[(c * NF + f) * NPTS + n];

        const float den = np_norm_den(v);
        float* fo = feats + (size_t)t * DIM;
        #pragma unroll
        for (int d = 0; d < DIM; ++d) { fn[d] = v[d] / den; fo[d] = fn[d]; }
    }

    u16* ho = fhi + (size_t)t * KPAD;
    u16* lo = flo + (size_t)t * KPAD;
    #pragma unroll
    for (int d = 0; d < DIM; ++d) {
        const u16 hb = bf16_rne(fn[d]);
        const float hf = __uint_as_float((u32)hb << 16);
        ho[d] = hb;
        lo[d] = bf16_rne(fn[d] - hf);
    }
    #pragma unroll
    for (int d = DIM; d < KPAD; ++d) { ho[d] = 0; lo[d] = 0; }

    const int flow = flow_p[0];
    float* ro = raw + (size_t)t * CCH;
    #pragma unroll
    for (int c = 0; c < CCH; ++c) {
        const float xv = flow ? v[CCH + c] : v[c];
        ro[c] = xv;
        out[TGT_BASE + ((size_t)b * CCH + c) * NPTS + n] = xv;
    }
}

// ---------------------------------------------------------------------------
// Fused kernel: block = (b, 64-row chunk), 1024 thr = 16 waves; lane = row.
// MFMA split-bf16 (hihi+hilo+lohi) approx dots; |approx-exact| <= eps ~1.2e-4.
// Pass 1 (SUBSET): waves scan only the first 1024 cands (4 tiles each) ->
// per-row top-16 approx VALUES -> tournament -> lb = subset 16th-largest.
// lb <= v16_full, so thr = lb - 8e-4 still satisfies the margin proof
// (8e-4 >= 2*eps) -> all true top-16 pass the filter. Survivors ~32/row.
// Pass 2: all 2048 cands, compare in C-fragment registers, sparse append.
// Exact rescue (bit-exact fp32 chain) + parallel rank-select + gather.
// ---------------------------------------------------------------------------
__global__ __launch_bounds__(1024) void fused_topk_kernel(
    const float* __restrict__ feats,
    const u16*   __restrict__ fhi,
    const u16*   __restrict__ flo,
    const float* __restrict__ raw,
    float*       __restrict__ out)
{
    __shared__ union {
        float cval[NWV * 16 * RS];   // 72 KiB: pass-1 C tiles, then vkeys[NWV][KTOP][64]
        u64   ckey[64 * CBS];        // 56.5 KiB: pass-2 survivors (alias, disjoint in time)
    } sh;
    __shared__ float thr_s[64];
    __shared__ int   cnt[64];
    __shared__ int   sel[64][KTOP];

    const int tid  = threadIdx.x;
    const int lane = tid & 63;
    const int w    = __builtin_amdgcn_readfirstlane(tid >> 6);
    const int b     = blockIdx.x >> 5;
    const int chunk = blockIdx.x & 31;
    const int rb    = chunk * 64;            // row base within batch
    const int p     = lane & 15;             // frag row/col within 16
    const int q     = lane >> 4;             // frag quad

    if (tid < 64) cnt[tid] = 0;

    // A fragments (this block's 64 rows = 4 m-tiles), hi/lo, persistent
    short8 ahi[4], alo[4];
    #pragma unroll
    for (int m = 0; m < 4; ++m) {
        const size_t ae = ((size_t)(b * NPTS + rb + m * 16 + p)) * KPAD + q * 8;
        ahi[m] = *(const short8*)(fhi + ae);
        alo[m] = *(const short8*)(flo + ae);
    }

    float* wval = sh.cval + w * (16 * RS);   // private C tile [16 cand][RS]

    float vlist[KTOP];
    #pragma unroll
    for (int k = 0; k < KTOP; ++k) vlist[k] = -3.0f;

    // ---- Pass 1 (subset: first 1024 cands; wave w -> [w*64, w*64+64)) ----
    {
        size_t be_n = ((size_t)(b * NPTS + w * 64 + p)) * KPAD + q * 8;
        short8 nbhi = *(const short8*)(fhi + be_n);
        short8 nblo = *(const short8*)(flo + be_n);
        for (int t = 0; t < 4; ++t) {
            const int cb0 = w * 64 + t * 16;     // cand base within batch
            const short8 bhi = nbhi, blo = nblo;
            if (t < 3) {                          // prefetch next tile
                const size_t be = ((size_t)(b * NPTS + cb0 + 16 + p)) * KPAD + q * 8;
                nbhi = *(const short8*)(fhi + be);
                nblo = *(const short8*)(flo + be);
            }
            #pragma unroll
            for (int m = 0; m < 4; ++m) {
                f32x4 acc = {0.0f, 0.0f, 0.0f, 0.0f};
                acc = __builtin_amdgcn_mfma_f32_16x16x32_bf16(ahi[m], bhi, acc, 0, 0, 0);
                acc = __builtin_amdgcn_mfma_f32_16x16x32_bf16(ahi[m], blo, acc, 0, 0, 0);
                acc = __builtin_amdgcn_mfma_f32_16x16x32_bf16(alo[m], bhi, acc, 0, 0, 0);
                *(f32x4*)(wval + p * RS + m * 16 + q * 4) = acc;
            }
            float bv[16];
            #pragma unroll
            for (int j = 0; j < 16; ++j) bv[j] = wval[j * RS + lane];
            // bitonic sort 16 ASC
            #pragma unroll
            for (int k = 2; k <= 16; k <<= 1)
                #pragma unroll
                for (int j = k >> 1; j > 0; j >>= 1)
                    #pragma unroll
                    for (int i = 0; i < 16; ++i) {
                        const int l = i | j;
                        if (l > i) {
                            const float a = bv[i], c = bv[l];
                            if ((i & k) == 0) { bv[i] = fminf(a, c); bv[l] = fmaxf(a, c); }
                            else              { bv[i] = fmaxf(a, c); bv[l] = fminf(a, c); }
                        }
                    }
            // merge (list desc + batch asc -> bitonic), cleanup desc
            #pragma unroll
            for (int i = 0; i < 16; ++i) vlist[i] = fmaxf(vlist[i], bv[i]);
            #pragma unroll
            for (int j = 8; j > 0; j >>= 1)
                #pragma unroll
                for (int i = 0; i < 16; ++i) {
                    const int l = i | j;
                    if (l > i) {
                        const float a = vlist[i], c = vlist[l];
                        vlist[i] = fmaxf(a, c);
                        vlist[l] = fminf(a, c);
                    }
                }
        }
    }

    __syncthreads();   // pass-1 tiles dead; cval reusable as vkeys

    // ---- tournament: 4 rounds of pairwise sorted-merge -> subset v16 ----
    float* vk = sh.cval;                     // vkeys[NWV][KTOP][64]
    for (int half = NWV / 2; half >= 1; half >>= 1) {
        if (w >= half && w < 2 * half) {
            #pragma unroll
            for (int k = 0; k < KTOP; ++k)
                vk[(w * KTOP + k) * 64 + lane] = vlist[k];
        }
        __syncthreads();
        if (w < half) {
            float other[KTOP];
            #pragma unroll
            for (int k = 0; k < KTOP; ++k)
                other[k] = vk[((w + half) * KTOP + k) * 64 + lane];
            #pragma unroll
            for (int i = 0; i < KTOP; ++i)
                vlist[i] = fmaxf(vlist[i], other[KTOP - 1 - i]);
            #pragma unroll
            for (int j = 8; j > 0; j >>= 1)
                #pragma unroll
                for (int i = 0; i < KTOP; ++i) {
                    const int l = i | j;
                    if (l > i) {
                        const float a = vlist[i], c = vlist[l];
                        vlist[i] = fmaxf(a, c);
                        vlist[l] = fminf(a, c);
                    }
                }
        }
        __syncthreads();
    }
    if (w == 0) thr_s[lane] = vlist[KTOP - 1] - 8e-4f;   // lb - 2*eps margin
    __syncthreads();                          // thr ready; vk dead -> ckey usable

    // per-position thresholds for this lane's C-fragment rows
    float thrv[4][4];
    #pragma unroll
    for (int m = 0; m < 4; ++m)
        #pragma unroll
        for (int i = 0; i < 4; ++i)
            thrv[m][i] = thr_s[m * 16 + q * 4 + i];

    // ---- Pass 2: all 2048 cands, register compare, sparse append ----
    {
        size_t be_n = ((size_t)(b * NPTS + w * 128 + p)) * KPAD + q * 8;
        short8 nbhi = *(const short8*)(fhi + be_n);
        short8 nblo = *(const short8*)(flo + be_n);
        for (int t = 0; t < 8; ++t) {
            const int cb0 = w * 128 + t * 16;
            const short8 bhi = nbhi, blo = nblo;
            if (t < 7) {                          // prefetch next tile
                const size_t be = ((size_t)(b * NPTS + cb0 + 16 + p)) * KPAD + q * 8;
                nbhi = *(const short8*)(fhi + be);
                nblo = *(const short8*)(flo + be);
            }
            #pragma unroll
            for (int m = 0; m < 4; ++m) {
                f32x4 acc = {0.0f, 0.0f, 0.0f, 0.0f};
                acc = __builtin_amdgcn_mfma_f32_16x16x32_bf16(ahi[m], bhi, acc, 0, 0, 0);
                acc = __builtin_amdgcn_mfma_f32_16x16x32_bf16(ahi[m], blo, acc, 0, 0, 0);
                acc = __builtin_amdgcn_mfma_f32_16x16x32_bf16(alo[m], bhi, acc, 0, 0, 0);
                #pragma unroll
                for (int i = 0; i < 4; ++i) {
                    if (acc[i] >= thrv[m][i]) {
                        const int r = m * 16 + q * 4 + i;   // row within chunk
                        const int pos = atomicAdd(&cnt[r], 1);
                        if (pos < CBUF)
                            sh.ckey[r * CBS + pos] = (u64)(u32)(cb0 + p);
                    }
                }
            }
        }
    }
    __syncthreads();

    // ---- exact rescue: bit-exact fp32 chain on survivors only ----
    {
        const float* fr = feats + (size_t)(b * NPTS + rb + lane) * DIM;
        float rfn[DIM];
        #pragma unroll
        for (int d = 0; d < DIM; ++d) rfn[d] = fr[d];
        const int e = (cnt[lane] < CBUF) ? cnt[lane] : CBUF;
        for (int pos = w; pos < e; pos += NWV) {
            const int idx = (int)(u32)sh.ckey[lane * CBS + pos];
            const float* cp = feats + (size_t)(b * NPTS + idx) * DIM;
            float acc = 0.0f;
            #pragma unroll
            for (int d = 0; d < DIM; ++d)
                acc = __builtin_fmaf(cp[d], rfn[d], acc);   // exact chain
            sh.ckey[lane * CBS + pos] = ((u64)ordf(acc) << 32) | (u32)(2047 - idx);
        }
    }
    __syncthreads();

    // ---- parallel rank-select: 16 threads per row ----
    {
        const int L = tid >> 4;
        const int g = tid & 15;
        const int e = (cnt[L] < CBUF) ? cnt[L] : CBUF;
        const u64* rowbuf = &sh.ckey[L * CBS];
        for (int pos = g; pos < e; pos += 16) {
            const u64 key = rowbuf[pos];
            int rank = 0;
            for (int p2 = 0; p2 < e; ++p2) rank += (rowbuf[p2] > key);
            if (rank < KTOP) sel[L][rank] = 2047 - (int)(key & 0xFFFFFFFFull);
        }
    }
    __syncthreads();

    // ---- gather: sx_c[b, n, k, c] = raw[(b*2048 + sel)*12 + c] ----
    const int rg = b * NPTS + rb;
    for (int e = tid; e < 64 * KTOP * CCH; e += 1024) {
        const int L = e / (KTOP * CCH);
        const int r = e % (KTOP * CCH);
        const int k = r / CCH;
        const int c = r % CCH;
        out[((size_t)(rg + L) * KTOP + k) * CCH + c] =
            raw[((size_t)b * NPTS + sel[L][k]) * CCH + c];
    }
}

// ---------------------------------------------------------------------------
extern "C" void kernel_launch(void* const* d_in, const int* in_sizes, int n_in,
                              void* d_out, int out_size, void* d_ws, size_t ws_size,
                              hipStream_t stream)
{
    const float* x_c    = (const float*)d_in[0];
    const int*   flow_p = (const int*)d_in[1];
    float*       out    = (float*)d_out;

    float* feats = (float*)((char*)d_ws + WS_FEATS);
    float* raw   = (float*)((char*)d_ws + WS_RAW);
    u16*   fhi   = (u16*)  ((char*)d_ws + WS_FHI);
    u16*   flo   = (u16*)  ((char*)d_ws + WS_FLO);

    prep_kernel<<<NROWS / 256, 256, 0, stream>>>(x_c, flow_p, feats, fhi, flo, raw, out);
    fused_topk_kernel<<<BS * 32, 1024, 0, stream>>>(feats, fhi, flo, raw, out);
}

// Round 14
// 101.584 us; speedup vs baseline: 1.8052x; 1.0375x over previous
//
#include <hip/hip_runtime.h>
#include <hip/hip_bf16.h>
#include <math.h>

#define BS   8
#define NPTS 2048
#define CCH  12      // channels per flow
#define NF   2       // flow dim
#define DIM  24      // NF*CCH, feats order: d = f*12 + c
#define KPAD 32      // MFMA K (24 + 8 zero pad)
#define KTOP 16
#define NWV  8       // waves per fused block (512 threads)
#define RPB  16      // rows per block (one m-tile)
#define CBUF 112     // survivor slots per row (~32 expected, +9.5 sigma)
#define CBS  113     // padded stride
#define WVS  20      // padded row stride of per-wave C tile (16B-aligned)

#define NROWS    (BS * NPTS)
#define TGT_BASE (NROWS * KTOP * CCH)   // 3145728

typedef unsigned long long u64;
typedef unsigned int       u32;
typedef unsigned short     u16;
typedef __attribute__((ext_vector_type(8))) short short8;   // bf16x8 MFMA frag
typedef __attribute__((ext_vector_type(4))) float f32x4;

// ws layout (bytes)
#define WS_FEATS 0                                  // fp32 [NROWS][24]
#define WS_RAW   (NROWS * DIM * 4)                  // fp32 [NROWS][12]
#define WS_FHI   (WS_RAW + NROWS * CCH * 4)         // bf16 [NROWS][32]
#define WS_FLO   (WS_FHI + NROWS * KPAD * 2)        // bf16 [NROWS][32]

// Emulate np.linalg.norm(v) + 1e-8 in float32 exactly (numpy pairwise sum, n=24)
__device__ __forceinline__ float np_norm_den(const float* __restrict__ v)
{
#pragma clang fp contract(off)
    float s[DIM];
    #pragma unroll
    for (int d = 0; d < DIM; ++d) s[d] = v[d] * v[d];
    float r[8];
    #pragma unroll
    for (int j = 0; j < 8; ++j) r[j] = (s[j] + s[j + 8]) + s[j + 16];
    float res = ((r[0] + r[1]) + (r[2] + r[3])) + ((r[4] + r[5]) + (r[6] + r[7]));
    return sqrtf(res) + 1e-8f;
}

// Monotone float -> u32 (preserves total order for finite floats)
__device__ __forceinline__ u32 ordf(float f)
{
    u32 u = __float_as_uint(f);
    return ((int)u >= 0) ? (u | 0x80000000u) : ~u;
}

// round-to-nearest-even fp32 -> bf16 bits (finite inputs)
__device__ __forceinline__ u16 bf16_rne(float x)
{
    u32 bits = __float_as_uint(x);
    bits += 0x7fffu + ((bits >> 16) & 1u);
    return (u16)(bits >> 16);
}

// ---------------------------------------------------------------------------
// Kernel 0: normalize rows (numpy-exact fp32); write fp32 feats, bf16 hi/lo
// (K-padded to 32), raw flow slice, and the tgt_out output.  (unchanged)
// ---------------------------------------------------------------------------
__global__ __launch_bounds__(256) void prep_kernel(
    const float* __restrict__ x_c,     // [8][12][2][2048]
    const int*   __restrict__ flow_p,
    float*       __restrict__ feats,   // [NROWS][24] normalized fp32
    u16*         __restrict__ fhi,     // [NROWS][32] bf16 hi
    u16*         __restrict__ flo,     // [NROWS][32] bf16 lo
    float*       __restrict__ raw,     // [NROWS][12] raw flow slice
    float*       __restrict__ out)
{
    const int t = blockIdx.x * 256 + threadIdx.x;   // global row
    const int b = t >> 11;
    const int n = t & (NPTS - 1);
    const float* xb = x_c + (size_t)b * CCH * NF * NPTS;

    float v[DIM];
    float fn[DIM];
    {
#pragma clang fp contract(off)
        #pragma unroll
        for (int c = 0; c < CCH; ++c)
            #pragma unroll
            for (int f = 0; f < NF; ++f)
                v[f * CCH + c] = xb[(c * NF + f) * NPTS + n];

        const float den = np_norm_den(v);
        float* fo = feats + (size_t)t * DIM;
        #pragma unroll
        for (int d = 0; d < DIM; ++d) { fn[d] = v[d] / den; fo[d] = fn[d]; }
    }

    u16* ho = fhi + (size_t)t * KPAD;
    u16* lo = flo + (size_t)t * KPAD;
    #pragma unroll
    for (int d = 0; d < DIM; ++d) {
        const u16 hb = bf16_rne(fn[d]);
        const float hf = __uint_as_float((u32)hb << 16);
        ho[d] = hb;
        lo[d] = bf16_rne(fn[d] - hf);
    }
    #pragma unroll
    for (int d = DIM; d < KPAD; ++d) { ho[d] = 0; lo[d] = 0; }

    const int flow = flow_p[0];
    float* ro = raw + (size_t)t * CCH;
    #pragma unroll
    for (int c = 0; c < CCH; ++c) {
        const float xv = flow ? v[CCH + c] : v[c];
        ro[c] = xv;
        out[TGT_BASE + ((size_t)b * CCH + c) * NPTS + n] = xv;
    }
}

// 4-stage bitonic cleanup, desc (list must be bitonic)
#define CLEANUP_DESC(arr)                                         \
    _Pragma("unroll")                                             \
    for (int j_ = 8; j_ > 0; j_ >>= 1)                            \
        _Pragma("unroll")                                         \
        for (int i_ = 0; i_ < KTOP; ++i_) {                       \
            const int l_ = i_ | j_;                               \
            if (l_ > i_) {                                        \
                const float a_ = arr[i_], c_ = arr[l_];           \
                arr[i_] = fmaxf(a_, c_);                          \
                arr[l_] = fminf(a_, c_);                          \
            }                                                     \
        }

// ---------------------------------------------------------------------------
// Fused kernel: block = (b, 16-row chunk), 512 thr = 8 waves. 1024 blocks ->
// 4 blocks/CU x 8 waves = 8 waves/SIMD (2x R13's latency hiding).
// MFMA split-bf16 approx dots (|approx-exact| <= eps ~1.2e-4).
// Pass 1 (subset, first 1024 cands): wave w scans [w*128,+128) in 2 rounds of
// 4 tiles; per-lane (row=p, cand-quad=q) collects 16 values/round via a tiny
// per-wave LDS transpose, sort16+merge into per-lane top-16; shfl_xor(16,32)
// pairwise merges unify the 4 row-copies; 3-round LDS tournament over 8
// waves -> lb; thr = lb - 8e-4 (same margin proof as R13).
// Pass 2: all 2048 cands, compare in C-frag registers, sparse append.
// Exact rescue (bit-exact fp32 chain) + parallel rank-select + gather.
// ---------------------------------------------------------------------------
__global__ __launch_bounds__(512) void fused_topk_kernel(
    const float* __restrict__ feats,
    const u16*   __restrict__ fhi,
    const u16*   __restrict__ flo,
    const float* __restrict__ raw,
    float*       __restrict__ out)
{
    __shared__ union {
        float wval[NWV * 16 * WVS];   // 10 KiB: per-wave C tiles [w][cand16][row WVS]
        float vk[NWV * KTOP * 16];    // 8 KiB: tournament lists [w][k][row16]
        u64   ckey[RPB * CBS];        // 14.1 KiB: survivors (aliases, disjoint in time)
    } sh;
    __shared__ float thr_s[RPB];
    __shared__ int   cnt[RPB];
    __shared__ int   sel[RPB][KTOP];

    const int tid  = threadIdx.x;
    const int lane = tid & 63;
    const int w    = __builtin_amdgcn_readfirstlane(tid >> 6);  // 0..7
    const int b     = blockIdx.x >> 7;
    const int chunk = blockIdx.x & 127;
    const int rb    = chunk * RPB;           // row base within batch
    const int p     = lane & 15;             // A-row / C-col index
    const int q     = lane >> 4;             // quad

    if (tid < RPB) cnt[tid] = 0;

    // A fragments: 16 rows (one m-tile), hi/lo
    short8 ahi, alo;
    {
        const size_t ae = ((size_t)(b * NPTS + rb + p)) * KPAD + q * 8;
        ahi = *(const short8*)(fhi + ae);
        alo = *(const short8*)(flo + ae);
    }

    float* wv = sh.wval + w * (16 * WVS);    // private C tile [cand][row]

    float vlist[KTOP];
    #pragma unroll
    for (int k = 0; k < KTOP; ++k) vlist[k] = -3.0f;

    // ---- Pass 1 (subset: wave w scans [w*128, +128) in 2 rounds x 4 tiles) ----
    for (int ro = 0; ro < 2; ++ro) {
        float bv[16];
        #pragma unroll
        for (int t = 0; t < 4; ++t) {
            const int cb0 = w * 128 + ro * 64 + t * 16;
            const size_t be = ((size_t)(b * NPTS + cb0 + p)) * KPAD + q * 8;
            const short8 bhi = *(const short8*)(fhi + be);
            const short8 blo = *(const short8*)(flo + be);
            f32x4 acc = {0.0f, 0.0f, 0.0f, 0.0f};
            acc = __builtin_amdgcn_mfma_f32_16x16x32_bf16(ahi, bhi, acc, 0, 0, 0);
            acc = __builtin_amdgcn_mfma_f32_16x16x32_bf16(ahi, blo, acc, 0, 0, 0);
            acc = __builtin_amdgcn_mfma_f32_16x16x32_bf16(alo, bhi, acc, 0, 0, 0);
            // lane holds cand p, rows q*4+i  ->  store [cand][row]
            *(f32x4*)(wv + p * WVS + q * 4) = acc;
            // read back: this lane takes row p, cands q*4+i (values only)
            #pragma unroll
            for (int i = 0; i < 4; ++i)
                bv[t * 4 + i] = wv[(q * 4 + i) * WVS + p];
        }
        // bitonic sort 16 ASC
        #pragma unroll
        for (int k = 2; k <= 16; k <<= 1)
            #pragma unroll
            for (int j = k >> 1; j > 0; j >>= 1)
                #pragma unroll
                for (int i = 0; i < 16; ++i) {
                    const int l = i | j;
                    if (l > i) {
                        const float a = bv[i], c = bv[l];
                        if ((i & k) == 0) { bv[i] = fminf(a, c); bv[l] = fmaxf(a, c); }
                        else              { bv[i] = fmaxf(a, c); bv[l] = fminf(a, c); }
                    }
                }
        // merge (vlist desc + bv asc -> bitonic), cleanup desc
        #pragma unroll
        for (int i = 0; i < 16; ++i) vlist[i] = fmaxf(vlist[i], bv[i]);
        CLEANUP_DESC(vlist)
    }

    // ---- intra-wave merges: unify the 4 row-copies (g-quads) ----
    #pragma unroll
    for (int x = 16; x <= 32; x <<= 1) {
        float other[KTOP];
        #pragma unroll
        for (int k = 0; k < KTOP; ++k) other[k] = __shfl_xor(vlist[k], x);
        #pragma unroll
        for (int i = 0; i < KTOP; ++i)
            vlist[i] = fmaxf(vlist[i], other[KTOP - 1 - i]);
        CLEANUP_DESC(vlist)
    }

    __syncthreads();   // pass-1 tiles dead; alias as vk

    // ---- tournament over 8 waves: 3 rounds ----
    for (int half = NWV / 2; half >= 1; half >>= 1) {
        if (w >= half && w < 2 * half && q == 0) {
            #pragma unroll
            for (int k = 0; k < KTOP; ++k)
                sh.vk[(w * KTOP + k) * 16 + p] = vlist[k];
        }
        __syncthreads();
        if (w < half) {
            float other[KTOP];
            #pragma unroll
            for (int k = 0; k < KTOP; ++k)
                other[k] = sh.vk[((w + half) * KTOP + k) * 16 + p];
            #pragma unroll
            for (int i = 0; i < KTOP; ++i)
                vlist[i] = fmaxf(vlist[i], other[KTOP - 1 - i]);
            CLEANUP_DESC(vlist)
        }
        __syncthreads();
    }
    if (w == 0 && q == 0) thr_s[p] = vlist[KTOP - 1] - 8e-4f;   // lb - 2*eps
    __syncthreads();                          // thr ready; vk dead -> ckey usable

    // per-position thresholds for this lane's C-fragment rows (q*4+i)
    float thrv[4];
    #pragma unroll
    for (int i = 0; i < 4; ++i) thrv[i] = thr_s[q * 4 + i];

    // ---- Pass 2: all 2048 cands (wave w: [w*256,+256)), register compare ----
    {
        size_t be_n = ((size_t)(b * NPTS + w * 256 + p)) * KPAD + q * 8;
        short8 nbhi = *(const short8*)(fhi + be_n);
        short8 nblo = *(const short8*)(flo + be_n);
        for (int t = 0; t < 16; ++t) {
            const int cb0 = w * 256 + t * 16;
            const short8 bhi = nbhi, blo = nblo;
            if (t < 15) {                         // prefetch next tile
                const size_t be = ((size_t)(b * NPTS + cb0 + 16 + p)) * KPAD + q * 8;
                nbhi = *(const short8*)(fhi + be);
                nblo = *(const short8*)(flo + be);
            }
            f32x4 acc = {0.0f, 0.0f, 0.0f, 0.0f};
            acc = __builtin_amdgcn_mfma_f32_16x16x32_bf16(ahi, bhi, acc, 0, 0, 0);
            acc = __builtin_amdgcn_mfma_f32_16x16x32_bf16(ahi, blo, acc, 0, 0, 0);
            acc = __builtin_amdgcn_mfma_f32_16x16x32_bf16(alo, bhi, acc, 0, 0, 0);
            #pragma unroll
            for (int i = 0; i < 4; ++i) {
                if (acc[i] >= thrv[i]) {
                    const int r = q * 4 + i;            // row within chunk
                    const int pos = atomicAdd(&cnt[r], 1);
                    if (pos < CBUF)
                        sh.ckey[r * CBS + pos] = (u64)(u32)(cb0 + p);
                }
            }
        }
    }
    __syncthreads();

    // ---- exact rescue: bit-exact fp32 chain on survivors only ----
    {
        const int r = tid & 15;                  // row within chunk
        const float* fr = feats + (size_t)(b * NPTS + rb + r) * DIM;
        float rfn[DIM];
        #pragma unroll
        for (int d = 0; d < DIM; ++d) rfn[d] = fr[d];
        const int e = (cnt[r] < CBUF) ? cnt[r] : CBUF;
        for (int pos = tid >> 4; pos < e; pos += 32) {
            const int idx = (int)(u32)sh.ckey[r * CBS + pos];
            const float* cp = feats + (size_t)(b * NPTS + idx) * DIM;
            float acc = 0.0f;
            #pragma unroll
            for (int d = 0; d < DIM; ++d)
                acc = __builtin_fmaf(cp[d], rfn[d], acc);   // exact chain
            sh.ckey[r * CBS + pos] = ((u64)ordf(acc) << 32) | (u32)(2047 - idx);
        }
    }
    __syncthreads();

    // ---- parallel rank-select: 32 threads per row ----
    {
        const int L = tid >> 5;                  // 0..15
        const int g = tid & 31;
        const int e = (cnt[L] < CBUF) ? cnt[L] : CBUF;
        const u64* rowbuf = &sh.ckey[L * CBS];
        for (int pos = g; pos < e; pos += 32) {
            const u64 key = rowbuf[pos];
            int rank = 0;
            for (int p2 = 0; p2 < e; ++p2) rank += (rowbuf[p2] > key);
            if (rank < KTOP) sel[L][rank] = 2047 - (int)(key & 0xFFFFFFFFull);
        }
    }
    __syncthreads();

    // ---- gather: sx_c[b, n, k, c] = raw[(b*2048 + sel)*12 + c] ----
    const int rg = b * NPTS + rb;
    for (int e2 = tid; e2 < RPB * KTOP * CCH; e2 += 512) {
        const int L = e2 / (KTOP * CCH);
        const int r = e2 % (KTOP * CCH);
        const int k = r / CCH;
        const int c = r % CCH;
        out[((size_t)(rg + L) * KTOP + k) * CCH + c] =
            raw[((size_t)b * NPTS + sel[L][k]) * CCH + c];
    }
}

// ---------------------------------------------------------------------------
extern "C" void kernel_launch(void* const* d_in, const int* in_sizes, int n_in,
                              void* d_out, int out_size, void* d_ws, size_t ws_size,
                              hipStream_t stream)
{
    const float* x_c    = (const float*)d_in[0];
    const int*   flow_p = (const int*)d_in[1];
    float*       out    = (float*)d_out;

    float* feats = (float*)((char*)d_ws + WS_FEATS);
    float* raw   = (float*)((char*)d_ws + WS_RAW);
    u16*   fhi   = (u16*)  ((char*)d_ws + WS_FHI);
    u16*   flo   = (u16*)  ((char*)d_ws + WS_FLO);

    prep_kernel<<<NROWS / 256, 256, 0, stream>>>(x_c, flow_p, feats, fhi, flo, raw, out);
    fused_topk_kernel<<<BS * 128, 512, 0, stream>>>(feats, fhi, flo, raw, out);
}